// Round 1
// baseline (728.425 us; speedup 1.0000x reference)
//
#include <hip/hip_runtime.h>

// FullTensorProduct: N=4096 rows, MUL=64.
// in1,in2: (N, 256) fp32; out: (N, 45056) fp32.
// Row layout: [c000: 4096][c110: 4096][c011: 12288][c101: 12288][c111: 12288]
// Write-BW-bound: 738 MB out vs 8 MB in. All stores are aligned float4.

#define ROW_IN   256
#define ROW_OUT  45056

__global__ __launch_bounds__(256) void ftp_kernel(
    const float* __restrict__ in1,
    const float* __restrict__ in2,
    float* __restrict__ out)
{
    __shared__ float sa[ROW_IN];   // a0[0:64], a1 flat [64:256] (u*3+i)
    __shared__ float sb[ROW_IN];   // b0[0:64], b1 flat [64:256] (v*3+j)

    const int row = blockIdx.x;
    const int t   = threadIdx.x;

    sa[t] = in1[(size_t)row * ROW_IN + t];
    sb[t] = in2[(size_t)row * ROW_IN + t];
    __syncthreads();

    const float* a0 = sa;
    const float* a1 = sa + 64;   // a1[u*3+i]
    const float* b0 = sb;
    const float* b1 = sb + 64;   // b1[v*3+j]

    constexpr float INV_SQRT3 = 0.57735026918962576f;
    constexpr float INV_SQRT2 = 0.70710678118654752f;

    float4* __restrict__ outr = (float4*)(out + (size_t)row * ROW_OUT);
    // region bases in float4 units:
    // c000 @ 0 (1024), c110 @ 1024 (1024), c011 @ 2048 (3072),
    // c101 @ 5120 (3072), c111 @ 8192 (3072)

    // ---- c000: out[u*64+v] = a0[u]*b0[v] ----
    #pragma unroll
    for (int it = 0; it < 4; ++it) {
        const int f = t + it * 256;
        const int e = f << 2;
        const int u = e >> 6;
        const int v = e & 63;
        const float au = a0[u];
        float4 r;
        r.x = au * b0[v + 0];
        r.y = au * b0[v + 1];
        r.z = au * b0[v + 2];
        r.w = au * b0[v + 3];
        outr[f] = r;
    }

    // ---- c110: out[u*64+v] = dot3(a1[u], b1[v]) / sqrt3 ----
    #pragma unroll
    for (int it = 0; it < 4; ++it) {
        const int f = t + it * 256;
        const int e = f << 2;
        const int u = e >> 6;
        const int v = e & 63;
        const float ax = a1[u * 3 + 0];
        const float ay = a1[u * 3 + 1];
        const float az = a1[u * 3 + 2];
        float4 r;
        {
            const float* bv = b1 + (v + 0) * 3;
            r.x = (ax * bv[0] + ay * bv[1] + az * bv[2]) * INV_SQRT3;
        }
        {
            const float* bv = b1 + (v + 1) * 3;
            r.y = (ax * bv[0] + ay * bv[1] + az * bv[2]) * INV_SQRT3;
        }
        {
            const float* bv = b1 + (v + 2) * 3;
            r.z = (ax * bv[0] + ay * bv[1] + az * bv[2]) * INV_SQRT3;
        }
        {
            const float* bv = b1 + (v + 3) * 3;
            r.w = (ax * bv[0] + ay * bv[1] + az * bv[2]) * INV_SQRT3;
        }
        outr[1024 + f] = r;
    }

    // ---- c011: flat e in [0,12288): out[e] = a0[e/192] * b1f[e%192] ----
    #pragma unroll
    for (int it = 0; it < 12; ++it) {
        const int f = t + it * 256;
        const int e = f << 2;
        const int u  = e / 192;          // constant across the 4 lanes of this float4
        const int r0 = e - u * 192;
        const float au = a0[u];
        float4 r;
        r.x = au * b1[r0 + 0];
        r.y = au * b1[r0 + 1];
        r.z = au * b1[r0 + 2];
        r.w = au * b1[r0 + 3];
        outr[2048 + f] = r;
    }

    // ---- c101: flat e: u=e/192, rr=e%192, v=rr/3, i=rr%3; out = a1[u*3+i]*b0[v] ----
    #pragma unroll
    for (int it = 0; it < 12; ++it) {
        const int f = t + it * 256;
        const int e = f << 2;
        const int u  = e / 192;
        const int r0 = e - u * 192;
        const float* au = a1 + u * 3;
        float vals[4];
        #pragma unroll
        for (int j = 0; j < 4; ++j) {
            const int rr = r0 + j;
            const int v  = rr / 3;
            const int i  = rr - 3 * v;
            vals[j] = au[i] * b0[v];
        }
        float4 r;
        r.x = vals[0]; r.y = vals[1]; r.z = vals[2]; r.w = vals[3];
        outr[5120 + f] = r;
    }

    // ---- c111: flat e: u=e/192, rr=e%192, v=rr/3, k=rr%3;
    //      out = (a1[u] x b1[v])_k / sqrt2 ----
    #pragma unroll
    for (int it = 0; it < 12; ++it) {
        const int f = t + it * 256;
        const int e = f << 2;
        const int u  = e / 192;
        const int r0 = e - u * 192;
        const float* au = a1 + u * 3;
        float vals[4];
        #pragma unroll
        for (int j = 0; j < 4; ++j) {
            const int rr = r0 + j;
            const int v  = rr / 3;
            const int k  = rr - 3 * v;
            const int k1 = (k < 2) ? k + 1 : 0;
            const int k2 = (k1 < 2) ? k1 + 1 : 0;
            const float* bv = b1 + v * 3;
            vals[j] = (au[k1] * bv[k2] - au[k2] * bv[k1]) * INV_SQRT2;
        }
        float4 r;
        r.x = vals[0]; r.y = vals[1]; r.z = vals[2]; r.w = vals[3];
        outr[8192 + f] = r;
    }
}

extern "C" void kernel_launch(void* const* d_in, const int* in_sizes, int n_in,
                              void* d_out, int out_size, void* d_ws, size_t ws_size,
                              hipStream_t stream) {
    const float* in1 = (const float*)d_in[0];
    const float* in2 = (const float*)d_in[1];
    float* out = (float*)d_out;
    const int N = in_sizes[0] / ROW_IN;   // 4096
    ftp_kernel<<<N, 256, 0, stream>>>(in1, in2, out);
}